// Round 15
// baseline (55.832 us; speedup 1.0000x reference)
//
#include <hip/hip_runtime.h>

#define B_ 16
#define A_ 3
#define G_ 76
#define GG_ (G_*G_)             // 5776
#define NC_ 80
#define C_ 85
#define NCELL (B_*A_*GG_)       // 277248
#define OUTN ((size_t)NCELL*C_) // 23566080
#define NBLKM (NCELL/32)        // 8664 blocks, 32 cells (2 waves x 16 cells); 8664%8==0
#define WSLOT 340               // f4 slots per wave (85 ch x 4 quads)

typedef float f4 __attribute__((ext_vector_type(4)));

__device__ __forceinline__ float sigf(float v){ return 1.0f/(1.0f + __expf(-v)); }
__device__ __forceinline__ float clog_(float p){ return fmaxf(__logf(p), -100.0f); }
__device__ __forceinline__ float bcef(float p, float t){ return -(t*clog_(p) + (1.0f-t)*clog_(1.0f-p)); }

// ---------------- mega: wave-private vectorized transpose + transform + fused loss ----------
// Wave owns 16 cells (16 | GG_, so one (b,a) plane per wave). Slot s in [0,340):
// k = s>>2 (channel), q = s&3 (cell quad). Quads (4 | G_) never cross rows.
// 128-thread blocks: 11.2 KB LDS -> 14 blocks/CU by LDS, 28 waves/CU.
__global__ __launch_bounds__(128, 7) void mega_kernel(
        const float* __restrict__ x, const float* __restrict__ iou,
        const unsigned int* __restrict__ om, const unsigned int* __restrict__ nm,
        const float* __restrict__ tw, const float* __restrict__ th,
        const float* __restrict__ tcls, const float* __restrict__ tconf,
        const float* __restrict__ tbox,
        float* __restrict__ out, float* __restrict__ partials){
    __shared__ __align__(16) float lds[2][16*C_];   // wave-private patches (10880 B)
    __shared__ float praw[32][2];                   // raw pw, ph per cell
    __shared__ float sred[2][6];

    const int tid  = (int)threadIdx.x;
    const int w    = tid >> 6;
    const int lane = tid & 63;

    // XCD-chunked swizzle (NBLKM % 8 == 0)
    int blk = ((int)blockIdx.x & 7)*(NBLKM/8) + ((int)blockIdx.x >> 3);

    int nw  = blk*32 + w*16;         // wave's first cell
    int ba  = nw / GG_;              // uniform per wave
    int ijw = nw - ba*GG_;           // uniform per wave (multiple of 16)
    int a   = ba % A_;
    float aw8 = (a==0)?12.0f:((a==1)?19.0f:40.0f);
    float ah8 = (a==0)?16.0f:((a==1)?36.0f:28.0f);
    const float* xw = x + (size_t)ba*C_*GG_ + (size_t)ijw;
    float* ldsw = lds[w];

    // ---- phase A1: stage wave's 340 f4 loads (wide, coalesced, no barrier needed) ----
    f4 rv[6];
    #pragma unroll
    for (int it=0; it<6; ++it){
        int s = lane + it*64;
        if (s < WSLOT){
            int k = s >> 2, q = s & 3;
            rv[it] = *(const f4*)(xw + (size_t)k*GG_ + 4*q);
        }
    }

    // ---- phase A2: transform + transposed scalar ds_writes into wave patch ----
    #pragma unroll
    for (int it=0; it<6; ++it){
        int s = lane + it*64;
        if (s < WSLOT){
            int k = s >> 2, q = s & 3;
            int ij0 = ijw + 4*q;
            f4 v = rv[it];
            f4 r;
            if (k >= 4){
                r[0]=sigf(v[0]); r[1]=sigf(v[1]); r[2]=sigf(v[2]); r[3]=sigf(v[3]);
            } else if (k == 0){
                float j0 = (float)(ij0 - (ij0/G_)*G_);
                r[0]=(sigf(v[0])+j0)*8.0f;      r[1]=(sigf(v[1])+j0+1.0f)*8.0f;
                r[2]=(sigf(v[2])+j0+2.0f)*8.0f; r[3]=(sigf(v[3])+j0+3.0f)*8.0f;
            } else if (k == 1){
                float fi = (float)(ij0/G_);
                r[0]=(sigf(v[0])+fi)*8.0f; r[1]=(sigf(v[1])+fi)*8.0f;
                r[2]=(sigf(v[2])+fi)*8.0f; r[3]=(sigf(v[3])+fi)*8.0f;
            } else if (k == 2){
                r[0]=__expf(v[0])*aw8; r[1]=__expf(v[1])*aw8;
                r[2]=__expf(v[2])*aw8; r[3]=__expf(v[3])*aw8;
                int c0 = w*16 + 4*q;
                praw[c0+0][0]=v[0]; praw[c0+1][0]=v[1];
                praw[c0+2][0]=v[2]; praw[c0+3][0]=v[3];
            } else { // k == 3
                r[0]=__expf(v[0])*ah8; r[1]=__expf(v[1])*ah8;
                r[2]=__expf(v[2])*ah8; r[3]=__expf(v[3])*ah8;
                int c0 = w*16 + 4*q;
                praw[c0+0][1]=v[0]; praw[c0+1][1]=v[1];
                praw[c0+2][1]=v[2]; praw[c0+3][1]=v[3];
            }
            int bix = 4*q*C_ + k;
            ldsw[bix]      = r[0];
            ldsw[bix+C_]   = r[1];
            ldsw[bix+2*C_] = r[2];
            ldsw[bix+3*C_] = r[3];
        }
    }

    // ---- phase B: wave patch -> contiguous cached f4 stores (no barrier) ----
    {
        const f4* src4 = (const f4*)ldsw;
        f4* dst4 = (f4*)(out + (size_t)nw*C_);     // 5440 B, 16B-aligned
        #pragma unroll
        for (int it=0; it<6; ++it){
            int s = lane + it*64;
            if (s < WSLOT) dst4[s] = src4[s];
        }
    }

    // ---- loss: 4 lanes per cell (qd splits 80 classes); qd0=CIoU, qd1=conf ----
    int lc = lane >> 2, qd = lane & 3;
    int n  = nw + lc;
    bool obj   = om[n] != 0u;     // 4-byte elements: int32 {0,1} or f32 {0,1.0f}
    bool noobj = nm[n] != 0u;
    const float* lrow = ldsw + lc*C_;

    float cls = 0.f;
    if (obj){
        const float* tcl = tcls + (size_t)n*NC_ + qd*20;
        const float* lp  = lrow + 5 + qd*20;
        #pragma unroll 4
        for (int j=0; j<20; ++j) cls += bcef(lp[j], tcl[j]);
    }
    cls += __shfl_xor(cls, 1, 64);
    cls += __shfl_xor(cls, 2, 64);
    if (qd != 0) cls = 0.f;

    float ciou=0.f, co=0.f, cn=0.f;
    if (qd == 0 && obj){
        float bx = lrow[0]*0.125f, by = lrow[1]*0.125f;
        float bw = lrow[2]*0.125f, bh = lrow[3]*0.125f;
        float rwv = praw[w*16+lc][0], rhv = praw[w*16+lc][1];
        float iouv = iou[n], twv = tw[n], thv = th[n];
        f4 tb = *(const f4*)(tbox + (size_t)n*4);
        float txc=tb[0], tyc=tb[1], twd=tb[2], tht=tb[3];
        float tx1 = txc - twd*0.5f, ty1 = tyc - tht*0.5f;
        float tx2 = txc + twd*0.5f, ty2 = tyc + tht*0.5f;
        float px1 = bx - bw*0.5f,  py1 = by - bh*0.5f;
        float px2 = bx + bw*0.5f,  py2 = by + bh*0.5f;
        float xc1 = fminf(px1, tx1), yc1 = fminf(py1, ty1);
        float xc2 = fmaxf(px2, tx2), yc2 = fmaxf(py2, ty2);
        float cc = (xc2-xc1)*(xc2-xc1) + (yc2-yc1)*(yc2-yc1) + 1e-7f;
        float dd = (txc-bx)*(txc-bx) + (tyc-by)*(tyc-by);
        float rdiou = dd/cc;
        float dat = atanf(twv/thv) - atanf(rwv/rhv);
        float vv = 0.40528473456935108577f * dat*dat;
        float Si = 1.0f - iouv;
        float alpha = vv/(Si+vv);
        ciou = 1.0f - iouv + rdiou + alpha*vv;
    }
    if (qd == 1 && (obj || noobj)){
        float bc = bcef(lrow[4], tconf[n]);
        co = obj ? bc : 0.f;
        cn = noobj ? bc : 0.f;
    }
    unsigned long long bo  = __ballot(obj   && qd == 0);   // one lane per cell
    unsigned long long bn2 = __ballot(noobj && qd == 1);

    float vals[4] = {ciou, co, cn, cls};
    #pragma unroll
    for (int q2=0; q2<4; ++q2){
        float v = vals[q2];
        #pragma unroll
        for (int o=32; o>0; o>>=1) v += __shfl_xor(v, o, 64);
        vals[q2] = v;
    }
    if (lane == 0){
        sred[w][0]=vals[0]; sred[w][1]=vals[1]; sred[w][2]=vals[2]; sred[w][3]=vals[3];
        sred[w][4]=(float)__popcll(bo); sred[w][5]=(float)__popcll(bn2);
    }
    __syncthreads();
    if (tid < 6)
        partials[(size_t)tid*NBLKM + blk] = sred[0][tid]+sred[1][tid];
}

// ---------------- final reduction ----------------
__global__ __launch_bounds__(256) void final_kernel(const float* __restrict__ partials,
                                                    float* __restrict__ out_loss){
    double acc[6] = {0,0,0,0,0,0};
    for (int idx = (int)threadIdx.x; idx < NBLKM; idx += 256){
        #pragma unroll
        for (int q=0;q<6;q++) acc[q] += (double)partials[(size_t)q*NBLKM + idx];
    }
    #pragma unroll
    for (int q=0;q<6;q++){
        double v = acc[q];
        #pragma unroll
        for (int o=32;o>0;o>>=1) v += __shfl_xor(v, o, 64);
        acc[q] = v;
    }
    __shared__ double smd[6][4];
    int lane = (int)threadIdx.x & 63, wid = (int)threadIdx.x >> 6;
    if (lane == 0){
        #pragma unroll
        for (int q=0;q<6;q++) smd[q][wid] = acc[q];
    }
    __syncthreads();
    if (threadIdx.x == 0){
        double s[6];
        #pragma unroll
        for (int q=0;q<6;q++) s[q] = smd[q][0]+smd[q][1]+smd[q][2]+smd[q][3];
        double cnt_o = fmax(s[4], 1.0);
        double cnt_n = fmax(s[5], 1.0);
        double total = s[0]/(double)B_
                     + s[1]/cnt_o
                     + 100.0*s[2]/cnt_n
                     + s[3]/(cnt_o*(double)NC_);
        *out_loss = (float)total;
    }
}

extern "C" void kernel_launch(void* const* d_in, const int* in_sizes, int n_in,
                              void* d_out, int out_size, void* d_ws, size_t ws_size,
                              hipStream_t stream){
    const float* x     = (const float*)d_in[0];
    const float* iou   = (const float*)d_in[1];
    const unsigned int* om = (const unsigned int*)d_in[2];
    const unsigned int* nm = (const unsigned int*)d_in[3];
    const float* tw    = (const float*)d_in[4];
    const float* th    = (const float*)d_in[5];
    const float* tcls  = (const float*)d_in[6];
    const float* tconf = (const float*)d_in[7];
    const float* tbox  = (const float*)d_in[8];
    float* out = (float*)d_out;

    float* partials = (float*)d_ws;

    mega_kernel<<<NBLKM, 128, 0, stream>>>(x, iou, om, nm, tw, th, tcls, tconf, tbox,
                                           out, partials);
    final_kernel<<<1, 256, 0, stream>>>(partials, out + OUTN);
}

// Round 16
// 54.613 us; speedup vs baseline: 1.0223x; 1.0223x over previous
//
#include <hip/hip_runtime.h>

#define B_ 16
#define A_ 3
#define G_ 76
#define GG_ (G_*G_)             // 5776
#define NC_ 80
#define C_ 85
#define NCELL (B_*A_*GG_)       // 277248
#define OUTN ((size_t)NCELL*C_) // 23566080
#define NBLK (NCELL/128)        // 2166 blocks; 4 waves x 32 cells (2 tiles of 16)
#define WSLOT 340               // f4 slots per 16-cell tile (85 ch x 4 quads)

typedef float f4 __attribute__((ext_vector_type(4)));

__device__ __forceinline__ float sigf(float v){ return 1.0f/(1.0f + __expf(-v)); }
__device__ __forceinline__ float clog_(float p){ return fmaxf(__logf(p), -100.0f); }
__device__ __forceinline__ float bcef(float p, float t){ return -(t*clog_(p) + (1.0f-t)*clog_(1.0f-p)); }

// ---------------- mega: 2-tile pipelined wave-private transpose + transform + loss --------
// Wave owns 32 cells = two 16-cell tiles (16 | GG_ so each tile sits in one (b,a) plane;
// tiles may straddle planes, so per-tile ba/ij). All 12 f4 loads + mask/tconf issued up
// front; tile-1 compute hides tile-2 load latency. LDS patch reused across tiles (DS ops
// are in-order within a wave -> no barriers).
__global__ __launch_bounds__(256, 4) void mega_kernel(
        const float* __restrict__ x, const float* __restrict__ iou,
        const unsigned int* __restrict__ om, const unsigned int* __restrict__ nm,
        const float* __restrict__ tw, const float* __restrict__ th,
        const float* __restrict__ tcls, const float* __restrict__ tconf,
        const float* __restrict__ tbox,
        float* __restrict__ out, float* __restrict__ partials){
    __shared__ __align__(16) float lds[4][16*C_];   // wave-private patches
    __shared__ float praw[4][16][2];                // wave-private raw pw/ph (per tile, reused)
    __shared__ float sred[4][6];

    const int tid  = (int)threadIdx.x;
    const int w    = tid >> 6;
    const int lane = tid & 63;

    // bijective XCD-chunked swizzle (NBLK % 8 == 6)
    unsigned qq = NBLK >> 3, rr = NBLK & 7u;
    unsigned xcd = blockIdx.x & 7u, seq = blockIdx.x >> 3;
    int blk = (int)((xcd < rr ? xcd*(qq+1u) : rr*(qq+1u) + (xcd-rr)*qq) + seq);

    int nwave = blk*128 + w*32;      // wave's first cell
    float* ldsw = lds[w];

    // ---- stage ALL loads up front: 12 tile f4s + both tiles' mask/tconf ----
    f4 rv[2][6];
    #pragma unroll
    for (int t=0; t<2; ++t){
        int nt = nwave + t*16;
        int ba = nt / GG_;
        int ij = nt - ba*GG_;
        const float* xw = x + (size_t)ba*C_*GG_ + (size_t)ij;
        #pragma unroll
        for (int it=0; it<6; ++it){
            int s = lane + it*64;
            if (s < WSLOT){
                int k = s >> 2, q = s & 3;
                rv[t][it] = *(const f4*)(xw + (size_t)k*GG_ + 4*q);
            }
        }
    }
    const int lc = lane >> 2, qd = lane & 3;
    bool objt[2], nobt[2];
    float tcf[2];
    #pragma unroll
    for (int t=0; t<2; ++t){
        int n = nwave + t*16 + lc;
        objt[t] = om[n] != 0u;      // 4-byte mask elements (int32 {0,1} / f32 {0,1.0f})
        nobt[t] = nm[n] != 0u;
        tcf[t]  = tconf[n];
    }

    float accC=0.f, accO=0.f, accN=0.f, accL=0.f, cntO=0.f, cntN=0.f;

    #pragma unroll
    for (int t=0; t<2; ++t){
        int nt  = nwave + t*16;
        int ba  = nt / GG_;
        int ijw = nt - ba*GG_;
        int a   = ba % A_;
        float aw8 = (a==0)?12.0f:((a==1)?19.0f:40.0f);
        float ah8 = (a==0)?16.0f:((a==1)?36.0f:28.0f);

        // ---- transform + transposed scalar ds_writes ----
        #pragma unroll
        for (int it=0; it<6; ++it){
            int s = lane + it*64;
            if (s < WSLOT){
                int k = s >> 2, q = s & 3;
                int ij0 = ijw + 4*q;
                f4 v = rv[t][it];
                f4 r;
                if (k >= 4){
                    r[0]=sigf(v[0]); r[1]=sigf(v[1]); r[2]=sigf(v[2]); r[3]=sigf(v[3]);
                } else if (k == 0){
                    float j0 = (float)(ij0 - (ij0/G_)*G_);
                    r[0]=(sigf(v[0])+j0)*8.0f;      r[1]=(sigf(v[1])+j0+1.0f)*8.0f;
                    r[2]=(sigf(v[2])+j0+2.0f)*8.0f; r[3]=(sigf(v[3])+j0+3.0f)*8.0f;
                } else if (k == 1){
                    float fi = (float)(ij0/G_);
                    r[0]=(sigf(v[0])+fi)*8.0f; r[1]=(sigf(v[1])+fi)*8.0f;
                    r[2]=(sigf(v[2])+fi)*8.0f; r[3]=(sigf(v[3])+fi)*8.0f;
                } else if (k == 2){
                    r[0]=__expf(v[0])*aw8; r[1]=__expf(v[1])*aw8;
                    r[2]=__expf(v[2])*aw8; r[3]=__expf(v[3])*aw8;
                    int c0 = 4*q;
                    praw[w][c0+0][0]=v[0]; praw[w][c0+1][0]=v[1];
                    praw[w][c0+2][0]=v[2]; praw[w][c0+3][0]=v[3];
                } else { // k == 3
                    r[0]=__expf(v[0])*ah8; r[1]=__expf(v[1])*ah8;
                    r[2]=__expf(v[2])*ah8; r[3]=__expf(v[3])*ah8;
                    int c0 = 4*q;
                    praw[w][c0+0][1]=v[0]; praw[w][c0+1][1]=v[1];
                    praw[w][c0+2][1]=v[2]; praw[w][c0+3][1]=v[3];
                }
                int bix = 4*q*C_ + k;
                ldsw[bix]      = r[0];
                ldsw[bix+C_]   = r[1];
                ldsw[bix+2*C_] = r[2];
                ldsw[bix+3*C_] = r[3];
            }
        }

        // ---- contiguous cached f4 stores ----
        {
            const f4* src4 = (const f4*)ldsw;
            f4* dst4 = (f4*)(out + (size_t)nt*C_);   // 5440 B, 16B-aligned
            #pragma unroll
            for (int it=0; it<6; ++it){
                int s = lane + it*64;
                if (s < WSLOT) dst4[s] = src4[s];
            }
        }

        // ---- loss for this tile's 16 cells (4 lanes/cell) ----
        bool obj = objt[t], noobj = nobt[t];
        int n = nt + lc;
        const float* lrow = ldsw + lc*C_;
        if (obj){
            const float* tcl = tcls + (size_t)n*NC_ + qd*20;
            const float* lp  = lrow + 5 + qd*20;
            float cls = 0.f;
            #pragma unroll 4
            for (int j=0; j<20; ++j) cls += bcef(lp[j], tcl[j]);
            accL += cls;
        }
        if (qd == 0 && obj){
            float bx = lrow[0]*0.125f, by = lrow[1]*0.125f;
            float bw = lrow[2]*0.125f, bh = lrow[3]*0.125f;
            float rwv = praw[w][lc][0], rhv = praw[w][lc][1];
            float iouv = iou[n], twv = tw[n], thv = th[n];
            f4 tb = *(const f4*)(tbox + (size_t)n*4);
            float txc=tb[0], tyc=tb[1], twd=tb[2], tht=tb[3];
            float tx1 = txc - twd*0.5f, ty1 = tyc - tht*0.5f;
            float tx2 = txc + twd*0.5f, ty2 = tyc + tht*0.5f;
            float px1 = bx - bw*0.5f,  py1 = by - bh*0.5f;
            float px2 = bx + bw*0.5f,  py2 = by + bh*0.5f;
            float xc1 = fminf(px1, tx1), yc1 = fminf(py1, ty1);
            float xc2 = fmaxf(px2, tx2), yc2 = fmaxf(py2, ty2);
            float cc = (xc2-xc1)*(xc2-xc1) + (yc2-yc1)*(yc2-yc1) + 1e-7f;
            float dd = (txc-bx)*(txc-bx) + (tyc-by)*(tyc-by);
            float rdiou = dd/cc;
            float dat = atanf(twv/thv) - atanf(rwv/rhv);
            float vv = 0.40528473456935108577f * dat*dat;
            float Si = 1.0f - iouv;
            float alpha = vv/(Si+vv);
            accC += 1.0f - iouv + rdiou + alpha*vv;
        }
        if (qd == 1 && (obj || noobj)){
            float bc = bcef(lrow[4], tcf[t]);
            if (obj)   accO += bc;
            if (noobj) accN += bc;
        }
        cntO += (float)__popcll(__ballot(obj   && qd == 0));
        cntN += (float)__popcll(__ballot(noobj && qd == 1));
    }

    // ---- wave reduction (4 independent 6-step chains), block merge ----
    float vals[4] = {accC, accO, accN, accL};
    #pragma unroll
    for (int q2=0; q2<4; ++q2){
        float v = vals[q2];
        #pragma unroll
        for (int o=32; o>0; o>>=1) v += __shfl_xor(v, o, 64);
        vals[q2] = v;
    }
    if (lane == 0){
        sred[w][0]=vals[0]; sred[w][1]=vals[1]; sred[w][2]=vals[2]; sred[w][3]=vals[3];
        sred[w][4]=cntO;    sred[w][5]=cntN;
    }
    __syncthreads();
    if (tid < 6)
        partials[(size_t)tid*NBLK + blk] = sred[0][tid]+sred[1][tid]+sred[2][tid]+sred[3][tid];
}

// ---------------- final reduction ----------------
__global__ __launch_bounds__(256) void final_kernel(const float* __restrict__ partials,
                                                    float* __restrict__ out_loss){
    double acc[6] = {0,0,0,0,0,0};
    for (int idx = (int)threadIdx.x; idx < NBLK; idx += 256){
        #pragma unroll
        for (int q=0;q<6;q++) acc[q] += (double)partials[(size_t)q*NBLK + idx];
    }
    #pragma unroll
    for (int q=0;q<6;q++){
        double v = acc[q];
        #pragma unroll
        for (int o=32;o>0;o>>=1) v += __shfl_xor(v, o, 64);
        acc[q] = v;
    }
    __shared__ double smd[6][4];
    int lane = (int)threadIdx.x & 63, wid = (int)threadIdx.x >> 6;
    if (lane == 0){
        #pragma unroll
        for (int q=0;q<6;q++) smd[q][wid] = acc[q];
    }
    __syncthreads();
    if (threadIdx.x == 0){
        double s[6];
        #pragma unroll
        for (int q=0;q<6;q++) s[q] = smd[q][0]+smd[q][1]+smd[q][2]+smd[q][3];
        double cnt_o = fmax(s[4], 1.0);
        double cnt_n = fmax(s[5], 1.0);
        double total = s[0]/(double)B_
                     + s[1]/cnt_o
                     + 100.0*s[2]/cnt_n
                     + s[3]/(cnt_o*(double)NC_);
        *out_loss = (float)total;
    }
}

extern "C" void kernel_launch(void* const* d_in, const int* in_sizes, int n_in,
                              void* d_out, int out_size, void* d_ws, size_t ws_size,
                              hipStream_t stream){
    const float* x     = (const float*)d_in[0];
    const float* iou   = (const float*)d_in[1];
    const unsigned int* om = (const unsigned int*)d_in[2];
    const unsigned int* nm = (const unsigned int*)d_in[3];
    const float* tw    = (const float*)d_in[4];
    const float* th    = (const float*)d_in[5];
    const float* tcls  = (const float*)d_in[6];
    const float* tconf = (const float*)d_in[7];
    const float* tbox  = (const float*)d_in[8];
    float* out = (float*)d_out;

    float* partials = (float*)d_ws;

    mega_kernel<<<NBLK, 256, 0, stream>>>(x, iou, om, nm, tw, th, tcls, tconf, tbox,
                                          out, partials);
    final_kernel<<<1, 256, 0, stream>>>(partials, out + OUTN);
}

// Round 20
// 48.947 us; speedup vs baseline: 1.1407x; 1.1158x over previous
//
#include <hip/hip_runtime.h>

#define B_ 16
#define A_ 3
#define G_ 76
#define GG_ (G_*G_)             // 5776
#define NC_ 80
#define C_ 85
#define NCELL (B_*A_*GG_)       // 277248
#define OUTN ((size_t)NCELL*C_) // 23566080
#define NBLKM (NCELL/64)        // 4332 blocks, 64 cells each

typedef float f4 __attribute__((ext_vector_type(4)));

__device__ __forceinline__ float sigf(float v){ return 1.0f/(1.0f + __expf(-v)); }
__device__ __forceinline__ float clog_(float p){ return fmaxf(__logf(p), -100.0f); }
__device__ __forceinline__ float bcef(float p, float t){ return -(t*clog_(p) + (1.0f-t)*clog_(1.0f-p)); }

// ---------------- mega: wave-private transpose + transform + fused loss ----------------
// Block = 64 cells (4 waves x 16 cells). Wave lanes: kg=lane>>4 (channel group), ci=lane&15 (cell).
// Masks: 4-byte elements; (word != 0) is correct for both int32 {0,1} and f32 {0,1.0f}.
__global__ __launch_bounds__(256, 7) void mega_kernel(
        const float* __restrict__ x, const float* __restrict__ iou,
        const unsigned int* __restrict__ om, const unsigned int* __restrict__ nm,
        const float* __restrict__ tw, const float* __restrict__ th,
        const float* __restrict__ tcls, const float* __restrict__ tconf,
        const float* __restrict__ tbox,
        float* __restrict__ out, float* __restrict__ partials){
    __shared__ __align__(16) float lds[4][16*C_];   // wave-private patches, flat [cell][channel]
    __shared__ float sred[4][6];

    const int tid  = (int)threadIdx.x;
    const int w    = tid >> 6;
    const int lane = tid & 63;
    const int kg   = lane >> 4;
    const int ci   = lane & 15;

    // bijective XCD-chunked swizzle (NBLKM % 8 == 4)
    unsigned qq = NBLKM >> 3, rr = NBLKM & 7u;
    unsigned xcd = blockIdx.x & 7u, seq = blockIdx.x >> 3;
    int blk = (int)((xcd < rr ? xcd*(qq+1u) : rr*(qq+1u) + (xcd-rr)*qq) + seq);

    int n0 = blk*64 + w*16;          // wave's first cell
    int n  = n0 + ci;                // lane's cell
    int ba = n / GG_;
    int ij = n - ba*GG_;
    int a  = ba % A_;
    int in_ = ij / G_;
    int jn  = ij - in_*G_;
    const float* xb = x + (size_t)ba*C_*GG_ + (size_t)ij;
    float* ldsw = lds[w];

    bool obj   = om[n] != 0u;
    bool noobj = nm[n] != 0u;

    const float* tcl = tcls + (size_t)n*NC_;
    float aw8 = (a==0)?12.0f:((a==1)?19.0f:40.0f);
    float ah8 = (a==0)?16.0f:((a==1)?36.0f:28.0f);

    float clsacc = 0.f;
    float pb0=0.f, pb1=0.f, pb2=0.f, pb3=0.f, rwv=0.f, rhv=0.f, pcf=0.f;

    // ---- phase A: load 4-channel groups, transform, cls-BCE from regs, scalar ds_writes ----
    const float* p = xb + (size_t)(4*kg)*GG_;
    #pragma unroll
    for (int it=0; it<5; ++it){
        float e0 = p[0];
        float e1 = p[(size_t)GG_];
        float e2 = p[(size_t)2*GG_];
        float e3 = p[(size_t)3*GG_];
        int kb = 16*it + 4*kg;
        float r0,r1,r2,r3;
        if (it==0 && kg==0){
            float s0 = sigf(e0), s1 = sigf(e1);
            r0 = (s0 + (float)jn)*8.0f;
            r1 = (s1 + (float)in_)*8.0f;
            r2 = __expf(e2)*aw8;
            r3 = __expf(e3)*ah8;
            pb0=r0; pb1=r1; pb2=r2; pb3=r3; rwv=e2; rhv=e3;
        } else {
            r0 = sigf(e0); r1 = sigf(e1); r2 = sigf(e2); r3 = sigf(e3);
            if (it==0 && kg==1) pcf = r0;
            if (obj){
                if (kb+0 >= 5) clsacc += bcef(r0, tcl[kb-5]);
                if (kb+1 >= 5) clsacc += bcef(r1, tcl[kb-4]);
                if (kb+2 >= 5) clsacc += bcef(r2, tcl[kb-3]);
                if (kb+3 >= 5) clsacc += bcef(r3, tcl[kb-2]);
            }
        }
        int bix = ci*C_ + kb;
        ldsw[bix+0] = r0;
        ldsw[bix+1] = r1;
        ldsw[bix+2] = r2;
        ldsw[bix+3] = r3;
        p += (size_t)16*GG_;
    }
    // tail: channels 80..84 (kg0: 80-83, kg1: 84; kg2/3 idle — no OOB loads)
    if (kg == 0){
        float e0=p[0], e1=p[(size_t)GG_], e2=p[(size_t)2*GG_], e3=p[(size_t)3*GG_];
        float q0=sigf(e0), q1=sigf(e1), q2=sigf(e2), q3=sigf(e3);
        int bix = ci*C_ + 80;
        ldsw[bix+0]=q0; ldsw[bix+1]=q1; ldsw[bix+2]=q2; ldsw[bix+3]=q3;
        if (obj) clsacc += bcef(q0,tcl[75]) + bcef(q1,tcl[76]) + bcef(q2,tcl[77]) + bcef(q3,tcl[78]);
    } else if (kg == 1){
        float e4 = p[0];
        float q4 = sigf(e4);
        ldsw[ci*C_ + 84] = q4;
        if (obj) clsacc += bcef(q4, tcl[79]);
    }

    // ---- phase B: flat LDS -> aligned coalesced float4 stores (no barrier; wave-private) ----
    {
        float* outw = out + (size_t)n0*C_;      // 5440B chunk, 16B-aligned
        const f4* src4 = (const f4*)ldsw;       // 1360 floats = 340 f4, contiguous
        f4* dst4 = (f4*)outw;
        #pragma unroll
        for (int itb=0; itb<6; ++itb){
            int f = lane + itb*64;
            if (f < 340) dst4[f] = src4[f];
        }
    }

    // ---- loss epilogue (registers only + tiny loads) ----
    float ciou=0.f, co=0.f, cn=0.f;
    if (kg==0 && obj){
        float iouv = iou[n], twv = tw[n], thv = th[n];
        f4 tb = *(const f4*)(tbox + (size_t)n*4);
        float bx = pb0*0.125f, by = pb1*0.125f, bw = pb2*0.125f, bh = pb3*0.125f;
        float txc=tb[0], tyc=tb[1], twd=tb[2], tht=tb[3];
        float tx1 = txc - twd*0.5f, ty1 = tyc - tht*0.5f;
        float tx2 = txc + twd*0.5f, ty2 = tyc + tht*0.5f;
        float px1 = bx - bw*0.5f,  py1 = by - bh*0.5f;
        float px2 = bx + bw*0.5f,  py2 = by + bh*0.5f;
        float xc1 = fminf(px1, tx1), yc1 = fminf(py1, ty1);
        float xc2 = fmaxf(px2, tx2), yc2 = fmaxf(py2, ty2);
        float cc = (xc2-xc1)*(xc2-xc1) + (yc2-yc1)*(yc2-yc1) + 1e-7f;
        float dd = (txc-bx)*(txc-bx) + (tyc-by)*(tyc-by);
        float rdiou = dd/cc;
        float dat = atanf(twv/thv) - atanf(rwv/rhv);
        float vv = 0.40528473456935108577f * dat*dat;
        float Si = 1.0f - iouv;
        float alpha = vv/(Si+vv);
        ciou = 1.0f - iouv + rdiou + alpha*vv;
    }
    if (kg==1 && (obj || noobj)){
        float bc = bcef(pcf, tconf[n]);
        co = obj ? bc : 0.f;
        cn = noobj ? bc : 0.f;
    }
    unsigned long long bo  = __ballot(obj)   & 0x00000000FFFF0000ULL;  // kg==1 lanes only
    unsigned long long bn2 = __ballot(noobj) & 0x00000000FFFF0000ULL;

    float vals[4] = {ciou, co, cn, clsacc};
    #pragma unroll
    for (int q2=0; q2<4; ++q2){
        float v = vals[q2];
        #pragma unroll
        for (int o=32; o>0; o>>=1) v += __shfl_xor(v, o, 64);
        vals[q2] = v;
    }
    if (lane == 0){
        sred[w][0]=vals[0]; sred[w][1]=vals[1]; sred[w][2]=vals[2]; sred[w][3]=vals[3];
        sred[w][4]=(float)__popcll(bo); sred[w][5]=(float)__popcll(bn2);
    }
    __syncthreads();
    if (tid < 6)
        partials[(size_t)tid*NBLKM + blk] = sred[0][tid]+sred[1][tid]+sred[2][tid]+sred[3][tid];
}

// ---------------- final reduction ----------------
__global__ __launch_bounds__(256) void final_kernel(const float* __restrict__ partials,
                                                    float* __restrict__ out_loss){
    double acc[6] = {0,0,0,0,0,0};
    for (int idx = (int)threadIdx.x; idx < NBLKM; idx += 256){
        #pragma unroll
        for (int q=0;q<6;q++) acc[q] += (double)partials[(size_t)q*NBLKM + idx];
    }
    #pragma unroll
    for (int q=0;q<6;q++){
        double v = acc[q];
        #pragma unroll
        for (int o=32;o>0;o>>=1) v += __shfl_xor(v, o, 64);
        acc[q] = v;
    }
    __shared__ double smd[6][4];
    int lane = (int)threadIdx.x & 63, wid = (int)threadIdx.x >> 6;
    if (lane == 0){
        #pragma unroll
        for (int q=0;q<6;q++) smd[q][wid] = acc[q];
    }
    __syncthreads();
    if (threadIdx.x == 0){
        double s[6];
        #pragma unroll
        for (int q=0;q<6;q++) s[q] = smd[q][0]+smd[q][1]+smd[q][2]+smd[q][3];
        double cnt_o = fmax(s[4], 1.0);
        double cnt_n = fmax(s[5], 1.0);
        double total = s[0]/(double)B_
                     + s[1]/cnt_o
                     + 100.0*s[2]/cnt_n
                     + s[3]/(cnt_o*(double)NC_);
        *out_loss = (float)total;
    }
}

extern "C" void kernel_launch(void* const* d_in, const int* in_sizes, int n_in,
                              void* d_out, int out_size, void* d_ws, size_t ws_size,
                              hipStream_t stream){
    const float* x     = (const float*)d_in[0];
    const float* iou   = (const float*)d_in[1];
    const unsigned int* om = (const unsigned int*)d_in[2];
    const unsigned int* nm = (const unsigned int*)d_in[3];
    const float* tw    = (const float*)d_in[4];
    const float* th    = (const float*)d_in[5];
    const float* tcls  = (const float*)d_in[6];
    const float* tconf = (const float*)d_in[7];
    const float* tbox  = (const float*)d_in[8];
    float* out = (float*)d_out;

    float* partials = (float*)d_ws;

    mega_kernel<<<NBLKM, 256, 0, stream>>>(x, iou, om, nm, tw, th, tcls, tconf, tbox,
                                           out, partials);
    final_kernel<<<1, 256, 0, stream>>>(partials, out + OUTN);
}